// Round 10
// baseline (491.306 us; speedup 1.0000x reference)
//
#include <hip/hip_runtime.h>
#include <hip/hip_fp16.h>
#include <math.h>

typedef _Float16 half8  __attribute__((ext_vector_type(8)));
typedef _Float16 half4v __attribute__((ext_vector_type(4)));
typedef float    f32x4  __attribute__((ext_vector_type(4)));

#define MFMA_F16 __builtin_amdgcn_mfma_f32_16x16x32_f16

namespace {

constexpr int M_ROWS = 128;                  // rows per block (4 waves x 128x64 tile)
// XOR-swizzled packed layouts (granule = 8 halves = 16 B):
//   Haddr(m,n) = m*256 + (((n>>3) ^ (m&7))<<3) + (n&7)     H: 128x256 = 64 KB
//   Paddr(m,k) = PE_OFF + m*64 + (((k>>3) ^ (m&7))<<3) + (k&7)   PE: 16 KB
// 80 KB/block -> 2 blocks/CU. R10 rationale: the 64x64 tile plateaus at
// MfmaUtil 37% because 78 cyc of MFMA/chunk can't hide ~200 cyc L2 latency
// on the weight loads. 128x64/wave doubles MFMA/chunk to 156 cyc (dist-1
// prefetch slack ~ L2 latency) and halves weight bytes per row. R8's version
// of this spilled at the 256-reg cap; fixed by (a) strict aP/aQ ping-pong +
// single JIT b[8] in the K-loop, (b) sigma written to global before c_0 so
// no head state lives across a do_layer.
constexpr int H_OFF      = 0;
constexpr int PE_OFF     = M_ROWS * 256;          // 32768 halves
constexpr int LDS_HALVES = PE_OFF + M_ROWS * 64;  // 40960 halves = 81920 B
constexpr size_t LDS_BYTES = (size_t)LDS_HALVES * sizeof(_Float16);

// Layer order: g1_0..g1_4, g2_0..g2_2, c_0, c_1, sig
constexpr int KCH_A[11] = {2,8,8,8,8,10,8,8,10,8,8};
constexpr int OFF_A[11] = {0,16384,81920,147456,212992,278528,360448,425984,491520,573440,577536};
constexpr int TOTAL_W   = 581632;   // fp16 elements in swizzled blob

struct Ptr11 { const float* p[11]; };

// ---------------------------------------------------------------------------
// Weight pre-swizzle (R7 layout): ntile innermost so a K-chunk's 4 a-loads
// share one pointer with 1024 B immediate offsets:
//   256-out layers: blob[((kc*16 + ntile)*64 + lane)*8 + j]
//   heads (L=9,10): blob[(kc*64 + lane)*8 + j]
// Fragment semantics: W[remap(kc*32 + (lane>>4)*8 + j)][ntile*16 + (lane&15)]
// as fp16, 0 if padded (A-frag for mfma_f32_16x16x32_f16).
// ---------------------------------------------------------------------------
__global__ void prep_kernel(Ptr11 wp, _Float16* __restrict__ ws) {
  int tid = blockIdx.x * blockDim.x + threadIdx.x;
  if (tid >= TOTAL_W) return;
  int L = 0;
#pragma unroll
  for (int i = 1; i < 11; ++i) if (tid >= OFF_A[i]) L = i;
  int e    = tid - OFF_A[L];
  int j    = e & 7;
  int lane = (e >> 3) & 63;
  int blk  = e >> 9;
  int kc, nt;
  if (L <= 8) { kc = blk >> 4; nt = blk & 15; }
  else        { kc = blk;      nt = 0; }
  int kpad = kc * 32 + ((lane >> 4) << 3) + j;
  int n    = nt * 16 + (lane & 15);
  int k;
  if      (L == 0) k = (kpad < 63) ? kpad : -1;                               // g1_0: din 63 pad->64
  else if (L == 5) k = (kpad < 64) ? ((kpad < 63) ? kpad : -1) : kpad - 1;    // g2_0: [pe_x 63|f1 256]
  else if (L == 8) k = (kpad < 64) ? ((kpad < 39) ? kpad : -1) : kpad - 25;   // c_0:  [pe_d 39|f2 256]
  else             k = kpad;                                                  // din 256 exact
  int dout = (L == 9) ? 3 : ((L == 10) ? 1 : 256);
  float v = 0.f;
  if (k >= 0 && n < dout) v = wp.p[L][k * dout + n];
  ws[tid] = (_Float16)v;
}

// ---------------------------------------------------------------------------
// One 256-out linear layer; wave cg (0..3) computes rows [0,128) x cols
// [cg*64, cg*64+64). Explicit aP/aQ ping-pong for the 4 global a-loads
// (dist-1 = 156 cyc slack) + single just-in-time b[8] from LDS (latency
// ~120 cyc, covered by fine-grained lgkmcnt against the 32-MFMA stream).
// All buffer indices compile-time (R1 lesson). Dual-base swizzle SR (R9):
// (u^c1)*32 == u*32 +/- c1*32 by parity -> ds_reads are base + literal.
// Live set: 128 AGPR acc + aP16 + aQ16 + b32 + ~16 addr ~= 230 < 256 cap.
// ---------------------------------------------------------------------------
template <int PE_CH, int H_CH, bool RELU>
__device__ __forceinline__ void do_layer(_Float16* lds,
                                         const _Float16* __restrict__ blob,
                                         const float* __restrict__ bias,
                                         int cg, int lane) {
  constexpr int KCH = PE_CH + H_CH;   // always even (2, 8, or 10)
  const int l15  = lane & 15;
  const int quad = lane >> 4;
  const int s7   = l15 & 7;          // swizzle key (row&7 == l15&7)
  const int c1   = s7 >> 2;          // chunk-granule xor bit
  const int q3   = (quad ^ (s7 & 3));

  f32x4 acc[8][4];
#pragma unroll
  for (int mt = 0; mt < 8; ++mt)
#pragma unroll
    for (int nt = 0; nt < 4; ++nt) acc[mt][nt] = (f32x4)0.f;

  half8 aP[4], aQ[4], b[8];

  const _Float16* ap = blob + ((size_t)(cg * 256 + lane)) * 8;
  const _Float16* pebase = lds + PE_OFF + l15 * 64 + q3 * 8;
  const _Float16* hbase  = lds + H_OFF  + l15 * 256 + q3 * 8;
  const int co = c1 << 5;            // 32-half parity correction
  const _Float16* peE = pebase + co;
  const _Float16* peO = pebase - co;
  const _Float16* hbE = hbase + co;
  const _Float16* hbO = hbase - co;

#define LOADA(dst, KCG)                                                       \
  {                                                                           \
    const _Float16* apk = ap + (size_t)(KCG) * 8192;                          \
    _Pragma("unroll") for (int nt = 0; nt < 4; ++nt)                          \
        dst[nt] = *(const half8*)(apk + nt * 512);                            \
  }

#define LOADB(KCG)                                                            \
  {                                                                           \
    if ((KCG) < PE_CH) {                                                      \
      const _Float16* bpp = (((KCG) & 1) ? peO : peE) + (KCG) * 32;           \
      _Pragma("unroll") for (int mt = 0; mt < 8; ++mt)                        \
          b[mt] = *(const half8*)(bpp + mt * 1024);                           \
    } else {                                                                  \
      const int U = (KCG) - PE_CH;                                            \
      const _Float16* bpp = ((U & 1) ? hbO : hbE) + U * 32;                   \
      _Pragma("unroll") for (int mt = 0; mt < 8; ++mt)                        \
          b[mt] = *(const half8*)(bpp + mt * 4096);                           \
    }                                                                         \
  }

#define DO_MFMA(ab)                                                           \
  {                                                                           \
    _Pragma("unroll") for (int mt = 0; mt < 8; ++mt)                          \
        _Pragma("unroll") for (int nt = 0; nt < 4; ++nt)                      \
            acc[mt][nt] = MFMA_F16(ab[nt], b[mt], acc[mt][nt], 0, 0, 0);      \
  }

  LOADA(aP, 0)
#pragma unroll
  for (int kk = 0; kk < KCH; kk += 2) {
    LOADB(kk)
    LOADA(aQ, kk + 1)
    DO_MFMA(aP)
    LOADB(kk + 1)
    if (kk + 2 < KCH) LOADA(aP, kk + 2)
    DO_MFMA(aQ)
  }
#undef LOADA
#undef LOADB
#undef DO_MFMA

  __syncthreads();   // all waves done READING H/PE before anyone overwrites H

  // Epilogue, SR: wa = mt*4096 + l15*256 + cg*64 + ((nt*2|qb)^s7)*8 + q1*4
  const int qb = quad >> 1, q1 = quad & 1;
  _Float16* wbase = lds + H_OFF + l15 * 256 + cg * 64 + q1 * 4;
  _Float16* wps[4] = { wbase + (((0 | qb) ^ s7) << 3),
                       wbase + (((2 | qb) ^ s7) << 3),
                       wbase + (((4 | qb) ^ s7) << 3),
                       wbase + (((6 | qb) ^ s7) << 3) };
#pragma unroll
  for (int mt = 0; mt < 8; ++mt) {
#pragma unroll
    for (int nt = 0; nt < 4; ++nt) {
      int n0 = cg * 64 + nt * 16 + quad * 4;
      f32x4 v = acc[mt][nt];
      f32x4 bb = *(const f32x4*)(bias + n0);
      v += bb;
      if (RELU) {
        v.x = fmaxf(v.x, 0.f); v.y = fmaxf(v.y, 0.f);
        v.z = fmaxf(v.z, 0.f); v.w = fmaxf(v.w, 0.f);
      }
      half4v hv = { (_Float16)v.x, (_Float16)v.y, (_Float16)v.z, (_Float16)v.w };
      *(half4v*)(wps[nt] + mt * 4096) = hv;
    }
  }
  __syncthreads();
}

// Head (sig / c_1): NT=1 blob, K=256 over H for the 16-row group at r0.
__device__ __forceinline__ f32x4 head_mt(const _Float16* lds,
                                         const _Float16* __restrict__ blob,
                                         int r0, int lane) {
  const int l15  = lane & 15;
  const int quad = lane >> 4;
  const int s7   = l15 & 7;
  const int c1   = s7 >> 2;
  const int q3   = (quad ^ (s7 & 3));
  const _Float16* hb = lds + H_OFF + (r0 + l15) * 256 + q3 * 8;
  f32x4 res = (f32x4)0.f;
#pragma unroll
  for (int kc = 0; kc < 8; ++kc) {
    half8 a = *(const half8*)(blob + (kc * 64 + lane) * 8);
    half8 b = *(const half8*)(hb + ((kc ^ c1) << 5));
    res = MFMA_F16(a, b, res, 0, 0, 0);
  }
  return res;
}

// Positional encoding: f = tid&63 loop-invariant -> classify once per thread.
// __sinf/__cosf: abs err ~1.5e-4, well under the f16 storage rounding.
__device__ __forceinline__ void pe_pass(_Float16* lds, const float* __restrict__ src,
                                        int row0, int tid, int nfeat) {
  const int f  = tid & 63;
  const int rb = tid >> 6;
  const int fg = f >> 3, f7 = f & 7;
  int mode, c = 0, use_cos = 0;
  float freq = 0.f;
  if (f < 3) { mode = 0; c = f; }
  else if (f < nfeat) {
    int g = f - 3, li = g / 6, rem = g - li * 6;
    use_cos = (rem >= 3); c = use_cos ? rem - 3 : rem;
    freq = (float)(1 << li); mode = 1;
  } else mode = 2;
  for (int t = 0; t < 32; ++t) {
    int r = rb + t * 4;
    float v = 0.f;
    if (mode == 0) v = src[(row0 + r) * 3 + c];
    else if (mode == 1) {
      float a = src[(row0 + r) * 3 + c] * freq;
      v = use_cos ? __cosf(a) : __sinf(a);
    }
    lds[PE_OFF + r * 64 + (((fg ^ (r & 7)) << 3) | f7)] = (_Float16)v;
  }
}

__global__ __launch_bounds__(256, 2) void nerf_kernel(
    const _Float16* __restrict__ ws, const float* __restrict__ x,
    const float* __restrict__ dirp, Ptr11 bp, float* __restrict__ out) {
  extern __shared__ _Float16 lds[];
  const int tid  = threadIdx.x;
  const int lane = tid & 63;
  const int w    = tid >> 6;       // wave 0..3 (= col-group cg)
  const int l15  = lane & 15;
  const int quad = lane >> 4;
  const int row0 = blockIdx.x * M_ROWS;

  // ---- pe_x -> PE buffer ----
  pe_pass(lds, x, row0, tid, 63);
  __syncthreads();

  // ---- G1: 63->256, 256->256 x4 (ReLU on all but last) ----
  do_layer<2, 0, true >(lds, ws + OFF_A[0], bp.p[0], w, lane);
  do_layer<0, 8, true >(lds, ws + OFF_A[1], bp.p[1], w, lane);
  do_layer<0, 8, true >(lds, ws + OFF_A[2], bp.p[2], w, lane);
  do_layer<0, 8, true >(lds, ws + OFF_A[3], bp.p[3], w, lane);
  do_layer<0, 8, false>(lds, ws + OFF_A[4], bp.p[4], w, lane);  // f1
  // ---- G2: [pe_x|f1] -> 256, 256->256, 256->256 (no ReLU on last) ----
  do_layer<2, 8, true >(lds, ws + OFF_A[5], bp.p[5], w, lane);  // pe_x last use
  do_layer<0, 8, true >(lds, ws + OFF_A[6], bp.p[6], w, lane);
  do_layer<0, 8, false>(lds, ws + OFF_A[7], bp.p[7], w, lane);  // f2

  // ---- sigma head: wave w covers rows [w*32, w*32+32); write straight to
  // global so no head state lives across c_0 (R8 spill source) ----
  {
    f32x4 sa0 = head_mt(lds, ws + OFF_A[10], w * 32,      lane);
    f32x4 sa1 = head_mt(lds, ws + OFF_A[10], w * 32 + 16, lane);
    if (quad == 0) {
      float sb = bp.p[10][0];
      out[(size_t)(row0 + w * 32 + l15) * 4 + 3]      = sa0[0] + sb;
      out[(size_t)(row0 + w * 32 + 16 + l15) * 4 + 3] = sa1[0] + sb;
    }
  }

  // ---- pe_d recompute into PE buffer (pe_x dead after g2_0) ----
  pe_pass(lds, dirp, row0, tid, 39);
  __syncthreads();   // PE writes visible; sig H-reads done (barrier covers both)

  // ---- color: [pe_d|f2] -> 256 (ReLU), then 256 -> 3 ----
  do_layer<2, 8, true>(lds, ws + OFF_A[8], bp.p[8], w, lane);
  {
    f32x4 ca0 = head_mt(lds, ws + OFF_A[9], w * 32,      lane);
    f32x4 ca1 = head_mt(lds, ws + OFF_A[9], w * 32 + 16, lane);
    if (quad == 0) {
      float b0 = bp.p[9][0], b1 = bp.p[9][1], b2 = bp.p[9][2];
      size_t i0 = (size_t)(row0 + w * 32 + l15) * 4;
      size_t i1 = (size_t)(row0 + w * 32 + 16 + l15) * 4;
      out[i0 + 0] = ca0[0] + b0; out[i0 + 1] = ca0[1] + b1; out[i0 + 2] = ca0[2] + b2;
      out[i1 + 0] = ca1[0] + b0; out[i1 + 1] = ca1[1] + b1; out[i1 + 2] = ca1[2] + b2;
    }
  }
}

}  // namespace

extern "C" void kernel_launch(void* const* d_in, const int* in_sizes, int n_in,
                              void* d_out, int out_size, void* d_ws, size_t ws_size,
                              hipStream_t stream) {
  const float* x   = (const float*)d_in[0];
  const float* dir = (const float*)d_in[1];
  Ptr11 wp, bp;
  for (int i = 0; i < 11; ++i) {
    wp.p[i] = (const float*)d_in[2 + 2 * i];
    bp.p[i] = (const float*)d_in[3 + 2 * i];
  }
  _Float16* ws = (_Float16*)d_ws;
  float* out = (float*)d_out;

  hipFuncSetAttribute((const void*)nerf_kernel,
                      hipFuncAttributeMaxDynamicSharedMemorySize, (int)LDS_BYTES);

  prep_kernel<<<TOTAL_W / 256, 256, 0, stream>>>(wp, ws);
  nerf_kernel<<<262144 / M_ROWS, 256, LDS_BYTES, stream>>>(ws, x, dir, bp, out);
}

// Round 11
// 416.471 us; speedup vs baseline: 1.1797x; 1.1797x over previous
//
#include <hip/hip_runtime.h>
#include <hip/hip_fp16.h>
#include <math.h>

typedef _Float16 half8  __attribute__((ext_vector_type(8)));
typedef _Float16 half4v __attribute__((ext_vector_type(4)));
typedef float    f32x4  __attribute__((ext_vector_type(4)));

#define MFMA_F16 __builtin_amdgcn_mfma_f32_16x16x32_f16

namespace {

constexpr int M_ROWS = 64;                   // rows per block (4 waves x 64x64 tile)
// XOR-swizzled packed layouts (granule = 8 halves = 16 B):
//   Haddr(m,n) = buf + m*256 + (((n>>3) ^ (m&7))<<3) + (n&7)   H: 2 x 32 KB
//   Paddr(m,k) = PE_OFF + m*64 + (((k>>3) ^ (m&7))<<3) + (k&7) PE: 8 KB
// R11: H double-buffer -> ONE barrier/layer (was 2); biases staged to LDS
// (f16) so the epilogue reads are a broadcast ds_read; K-loop tail prefetches
// the NEXT layer's chunk-0 A-frags (pure global, no H dep) so layer-boundary
// L2 latency hides behind epilogue+barrier. 76.5 KB -> 2 blocks/CU.
constexpr int B0_OFF   = 0;
constexpr int B1_OFF   = 16384;
constexpr int PE_OFF   = 32768;              // 64*64 = 4096 halves
constexpr int BIAS_OFF = 36864;              // 9 layers * 256 halves = 2304
constexpr int LDS_HALVES = BIAS_OFF + 2304;  // 39168 halves = 78336 B
constexpr size_t LDS_BYTES = (size_t)LDS_HALVES * sizeof(_Float16);

// Layer order: g1_0..g1_4, g2_0..g2_2, c_0, c_1, sig
constexpr int OFF_A[11] = {0,16384,81920,147456,212992,278528,360448,425984,491520,573440,577536};
constexpr int TOTAL_W   = 581632;   // fp16 elements in swizzled blob

struct Ptr11 { const float* p[11]; };

// ---------------------------------------------------------------------------
// Weight pre-swizzle (R7 layout, unchanged): ntile innermost; 256-out layers:
// blob[((kc*16 + ntile)*64 + lane)*8 + j]; heads: blob[(kc*64 + lane)*8 + j].
// Semantics: W[remap(kc*32 + (lane>>4)*8 + j)][ntile*16 + (lane&15)], fp16,
// 0 if padded (A-frag for mfma_f32_16x16x32_f16).
// ---------------------------------------------------------------------------
__global__ void prep_kernel(Ptr11 wp, _Float16* __restrict__ ws) {
  int tid = blockIdx.x * blockDim.x + threadIdx.x;
  if (tid >= TOTAL_W) return;
  int L = 0;
#pragma unroll
  for (int i = 1; i < 11; ++i) if (tid >= OFF_A[i]) L = i;
  int e    = tid - OFF_A[L];
  int j    = e & 7;
  int lane = (e >> 3) & 63;
  int blk  = e >> 9;
  int kc, nt;
  if (L <= 8) { kc = blk >> 4; nt = blk & 15; }
  else        { kc = blk;      nt = 0; }
  int kpad = kc * 32 + ((lane >> 4) << 3) + j;
  int n    = nt * 16 + (lane & 15);
  int k;
  if      (L == 0) k = (kpad < 63) ? kpad : -1;                               // g1_0: din 63 pad->64
  else if (L == 5) k = (kpad < 64) ? ((kpad < 63) ? kpad : -1) : kpad - 1;    // g2_0: [pe_x 63|f1 256]
  else if (L == 8) k = (kpad < 64) ? ((kpad < 39) ? kpad : -1) : kpad - 25;   // c_0:  [pe_d 39|f2 256]
  else             k = kpad;                                                  // din 256 exact
  int dout = (L == 9) ? 3 : ((L == 10) ? 1 : 256);
  float v = 0.f;
  if (k >= 0 && n < dout) v = wp.p[L][k * dout + n];
  ws[tid] = (_Float16)v;
}

// ---------------------------------------------------------------------------
// One 256-out linear layer; wave cg computes rows [0,64) x cols [cg*64,+64).
// K-loop: R9 dist-1 ping-pong for a AND b (all indices compile-time), dual-
// base swizzle SR. Reads H at rd, writes H at wr (the other buffer) -> no
// mid-layer barrier; single __syncthreads at the end. aE[] persists across
// layers: the tail LOADA targets nblob chunk 0 (cross-layer prefetch).
// ---------------------------------------------------------------------------
template <int PE_CH, int H_CH, bool RELU>
__device__ __forceinline__ void do_layer(_Float16* lds, int rd, int wr,
                                         const _Float16* __restrict__ blob,
                                         const _Float16* __restrict__ nblob,
                                         int bias_idx, int cg, int lane,
                                         half8 aE[4]) {
  constexpr int KCH = PE_CH + H_CH;   // even (2, 8, or 10)
  const int l15  = lane & 15;
  const int quad = lane >> 4;
  const int s7   = l15 & 7;          // swizzle key (row&7 == l15&7)
  const int c1   = s7 >> 2;          // chunk-granule xor bit
  const int q3   = (quad ^ (s7 & 3));

  f32x4 acc[4][4];
#pragma unroll
  for (int mt = 0; mt < 4; ++mt)
#pragma unroll
    for (int nt = 0; nt < 4; ++nt) acc[mt][nt] = (f32x4)0.f;

  half8 aO[4], bE[4], bO[4];

  const _Float16* ap  = blob  + ((size_t)(cg * 256 + lane)) * 8;
  const _Float16* nap = nblob + ((size_t)(cg * 256 + lane)) * 8;
  const _Float16* pebase = lds + PE_OFF + l15 * 64 + q3 * 8;
  const _Float16* hbase  = lds + rd + l15 * 256 + q3 * 8;
  const int co = c1 << 5;            // 32-half parity correction
  const _Float16* peE = pebase + co;
  const _Float16* peO = pebase - co;
  const _Float16* hbE = hbase + co;
  const _Float16* hbO = hbase - co;

#define LOADA(dst, base, KCG)                                                 \
  {                                                                           \
    const _Float16* apk = (base) + (size_t)(KCG) * 8192;                      \
    _Pragma("unroll") for (int nt = 0; nt < 4; ++nt)                          \
        dst[nt] = *(const half8*)(apk + nt * 512);                            \
  }

#define LOADB(bb, KCG)                                                        \
  {                                                                           \
    if ((KCG) < PE_CH) {                                                      \
      const _Float16* bpp = (((KCG) & 1) ? peO : peE) + (KCG) * 32;           \
      _Pragma("unroll") for (int mt = 0; mt < 4; ++mt)                        \
          bb[mt] = *(const half8*)(bpp + mt * 1024);                          \
    } else {                                                                  \
      const int U = (KCG) - PE_CH;                                            \
      const _Float16* bpp = ((U & 1) ? hbO : hbE) + U * 32;                   \
      _Pragma("unroll") for (int mt = 0; mt < 4; ++mt)                        \
          bb[mt] = *(const half8*)(bpp + mt * 4096);                          \
    }                                                                         \
  }

#define DO_MFMA(ab, bb)                                                       \
  {                                                                           \
    _Pragma("unroll") for (int mt = 0; mt < 4; ++mt)                          \
        _Pragma("unroll") for (int nt = 0; nt < 4; ++nt)                      \
            acc[mt][nt] = MFMA_F16(ab[nt], bb[mt], acc[mt][nt], 0, 0, 0);     \
  }

  LOADB(bE, 0)                       // b chunk 0 (can't cross the barrier)
#pragma unroll
  for (int kk = 0; kk < KCH; kk += 2) {
    LOADA(aO, ap, kk + 1)
    LOADB(bO, kk + 1)
    DO_MFMA(aE, bE)
    if (kk + 2 < KCH) {
      LOADA(aE, ap, kk + 2)
      LOADB(bE, kk + 2)
    } else {
      LOADA(aE, nap, 0)              // cross-layer prefetch of next chunk 0
    }
    DO_MFMA(aO, bO)
  }
#undef LOADA
#undef LOADB
#undef DO_MFMA

  // Epilogue: bias from LDS (broadcast ds_read, staged once at kernel start),
  // write to the OTHER H buffer -> no pre-epilogue barrier needed.
  const int qb = quad >> 1, q1 = quad & 1;
  _Float16* wbase = lds + wr + l15 * 256 + cg * 64 + q1 * 4;
  _Float16* wps[4] = { wbase + (((0 | qb) ^ s7) << 3),
                       wbase + (((2 | qb) ^ s7) << 3),
                       wbase + (((4 | qb) ^ s7) << 3),
                       wbase + (((6 | qb) ^ s7) << 3) };
  const _Float16* bb_ = lds + BIAS_OFF + bias_idx * 256 + cg * 64 + quad * 4;
  f32x4 bf[4];
#pragma unroll
  for (int nt = 0; nt < 4; ++nt) {
    half4v bh = *(const half4v*)(bb_ + nt * 16);
    bf[nt] = f32x4{ (float)bh[0], (float)bh[1], (float)bh[2], (float)bh[3] };
  }
#pragma unroll
  for (int mt = 0; mt < 4; ++mt) {
#pragma unroll
    for (int nt = 0; nt < 4; ++nt) {
      f32x4 v = acc[mt][nt] + bf[nt];
      if (RELU) {
        v.x = fmaxf(v.x, 0.f); v.y = fmaxf(v.y, 0.f);
        v.z = fmaxf(v.z, 0.f); v.w = fmaxf(v.w, 0.f);
      }
      half4v hv = { (_Float16)v.x, (_Float16)v.y, (_Float16)v.z, (_Float16)v.w };
      *(half4v*)(wps[nt] + mt * 4096) = hv;
    }
  }
  __syncthreads();   // writes to wr visible; everyone done reading rd
}

// Head (sig / c_1): NT=1 blob, K=256 over H at rd; wave w rows [w*16,+16).
__device__ __forceinline__ f32x4 head_mt(const _Float16* lds, int rd,
                                         const _Float16* __restrict__ blob,
                                         int w, int lane) {
  const int l15  = lane & 15;
  const int quad = lane >> 4;
  const int s7   = l15 & 7;
  const int c1   = s7 >> 2;
  const int q3   = (quad ^ (s7 & 3));
  const _Float16* hb = lds + rd + (w * 16 + l15) * 256 + q3 * 8;
  f32x4 res = (f32x4)0.f;
#pragma unroll
  for (int kc = 0; kc < 8; ++kc) {
    half8 a = *(const half8*)(blob + (kc * 64 + lane) * 8);
    half8 b = *(const half8*)(hb + ((kc ^ c1) << 5));
    res = MFMA_F16(a, b, res, 0, 0, 0);
  }
  return res;
}

// Positional encoding: f = tid&63 loop-invariant -> classify once per thread.
__device__ __forceinline__ void pe_pass(_Float16* lds, const float* __restrict__ src,
                                        int row0, int tid, int nfeat) {
  const int f  = tid & 63;
  const int rb = tid >> 6;
  const int fg = f >> 3, f7 = f & 7;
  int mode, c = 0, use_cos = 0;
  float freq = 0.f;
  if (f < 3) { mode = 0; c = f; }
  else if (f < nfeat) {
    int g = f - 3, li = g / 6, rem = g - li * 6;
    use_cos = (rem >= 3); c = use_cos ? rem - 3 : rem;
    freq = (float)(1 << li); mode = 1;
  } else mode = 2;
#pragma unroll
  for (int t = 0; t < 16; ++t) {
    int r = rb + t * 4;
    float v = 0.f;
    if (mode == 0) v = src[(row0 + r) * 3 + c];
    else if (mode == 1) {
      float a = src[(row0 + r) * 3 + c] * freq;
      v = use_cos ? __cosf(a) : __sinf(a);
    }
    lds[PE_OFF + r * 64 + (((fg ^ (r & 7)) << 3) | f7)] = (_Float16)v;
  }
}

__global__ __launch_bounds__(256, 2) void nerf_kernel(
    const _Float16* __restrict__ ws, const float* __restrict__ x,
    const float* __restrict__ dirp, Ptr11 bp, float* __restrict__ out) {
  extern __shared__ _Float16 lds[];
  const int tid  = threadIdx.x;
  const int lane = tid & 63;
  const int w    = tid >> 6;       // wave 0..3 (= col-group cg)
  const int l15  = lane & 15;
  const int quad = lane >> 4;
  const int row0 = blockIdx.x * M_ROWS;

  // ---- prefetch g1_0 chunk-0 A-frags (hides L2 latency behind pe_pass) ----
  half8 aE[4];
  {
    const _Float16* apk = ws + ((size_t)(w * 256 + lane)) * 8;
#pragma unroll
    for (int nt = 0; nt < 4; ++nt) aE[nt] = *(const half8*)(apk + nt * 512);
  }

  // ---- pe_x -> PE buffer; biases -> LDS (f16, once) ----
  pe_pass(lds, x, row0, tid, 63);
#pragma unroll
  for (int L = 0; L < 9; ++L)
    lds[BIAS_OFF + L * 256 + tid] = (_Float16)bp.p[L][tid];
  __syncthreads();

  // ---- G1 (rd/wr alternate B0/B1; f1 lands in B0) ----
  do_layer<2, 0, true >(lds, B0_OFF, B0_OFF, ws + OFF_A[0], ws + OFF_A[1], 0, w, lane, aE);
  do_layer<0, 8, true >(lds, B0_OFF, B1_OFF, ws + OFF_A[1], ws + OFF_A[2], 1, w, lane, aE);
  do_layer<0, 8, true >(lds, B1_OFF, B0_OFF, ws + OFF_A[2], ws + OFF_A[3], 2, w, lane, aE);
  do_layer<0, 8, true >(lds, B0_OFF, B1_OFF, ws + OFF_A[3], ws + OFF_A[4], 3, w, lane, aE);
  do_layer<0, 8, false>(lds, B1_OFF, B0_OFF, ws + OFF_A[4], ws + OFF_A[5], 4, w, lane, aE);
  // ---- G2: f2 lands in B1 ----
  do_layer<2, 8, true >(lds, B0_OFF, B1_OFF, ws + OFF_A[5], ws + OFF_A[6], 5, w, lane, aE);
  do_layer<0, 8, true >(lds, B1_OFF, B0_OFF, ws + OFF_A[6], ws + OFF_A[7], 6, w, lane, aE);
  do_layer<0, 8, false>(lds, B0_OFF, B1_OFF, ws + OFF_A[7], ws + OFF_A[8], 7, w, lane, aE);

  // ---- sigma head reads f2@B1; pe_d overwrites PE (pe_x dead) ----
  f32x4 sa = head_mt(lds, B1_OFF, ws + OFF_A[10], w, lane);
  float sigv = sa[0] + bp.p[10][0];   // valid in quad==0 lanes
  pe_pass(lds, dirp, row0, tid, 39);
  __syncthreads();   // pe_d visible before c_0

  // ---- color: c_0 [pe_d|f2@B1] -> B0 (ReLU), c_1 reads B0 ----
  do_layer<2, 8, true>(lds, B1_OFF, B0_OFF, ws + OFF_A[8], ws, 8, w, lane, aE);
  f32x4 ca = head_mt(lds, B0_OFF, ws + OFF_A[9], w, lane);
  if (quad == 0) {
    f32x4 o = { ca[0] + bp.p[9][0], ca[1] + bp.p[9][1], ca[2] + bp.p[9][2], sigv };
    *(f32x4*)(out + (size_t)(row0 + w * 16 + l15) * 4) = o;
  }
}

}  // namespace

extern "C" void kernel_launch(void* const* d_in, const int* in_sizes, int n_in,
                              void* d_out, int out_size, void* d_ws, size_t ws_size,
                              hipStream_t stream) {
  const float* x   = (const float*)d_in[0];
  const float* dir = (const float*)d_in[1];
  Ptr11 wp, bp;
  for (int i = 0; i < 11; ++i) {
    wp.p[i] = (const float*)d_in[2 + 2 * i];
    bp.p[i] = (const float*)d_in[3 + 2 * i];
  }
  _Float16* ws = (_Float16*)d_ws;
  float* out = (float*)d_out;

  hipFuncSetAttribute((const void*)nerf_kernel,
                      hipFuncAttributeMaxDynamicSharedMemorySize, (int)LDS_BYTES);

  prep_kernel<<<TOTAL_W / 256, 256, 0, stream>>>(wp, ws);
  nerf_kernel<<<262144 / M_ROWS, 256, LDS_BYTES, stream>>>(ws, x, dir, bp, out);
}

// Round 12
// 415.894 us; speedup vs baseline: 1.1813x; 1.0014x over previous
//
#include <hip/hip_runtime.h>
#include <hip/hip_fp16.h>
#include <math.h>

typedef _Float16 half8  __attribute__((ext_vector_type(8)));
typedef _Float16 half4v __attribute__((ext_vector_type(4)));
typedef float    f32x4  __attribute__((ext_vector_type(4)));

#define MFMA_F16 __builtin_amdgcn_mfma_f32_16x16x32_f16

namespace {

constexpr int M_ROWS = 64;                   // rows per block (4 waves x 64x64 tile)
// XOR-swizzled packed layouts (granule = 8 halves = 16 B):
//   Haddr(m,n) = buf + m*256 + (((n>>3) ^ (m&7))<<3) + (n&7)   H: 2 x 32 KB
//   Paddr(m,k) = PE_OFF + m*64 + (((k>>3) ^ (m&7))<<3) + (k&7) PE: 8 KB
// R12: same memory plan as R11 (dbuf H, one barrier/layer, bias in LDS).
// K-loop rescheduled to A-prefetch distance TWO (~620 cyc slack vs ~310):
// R2-R11 ensemble shows per-wave duty ~26% == dist-1 slack < effective
// congested L2 latency. Same two A buffers, just loaded post-consumption.
constexpr int B0_OFF   = 0;
constexpr int B1_OFF   = 16384;
constexpr int PE_OFF   = 32768;              // 64*64 = 4096 halves
constexpr int BIAS_OFF = 36864;              // 9 layers * 256 halves = 2304
constexpr int LDS_HALVES = BIAS_OFF + 2304;  // 39168 halves = 78336 B
constexpr size_t LDS_BYTES = (size_t)LDS_HALVES * sizeof(_Float16);

// Layer order: g1_0..g1_4, g2_0..g2_2, c_0, c_1, sig
constexpr int OFF_A[11] = {0,16384,81920,147456,212992,278528,360448,425984,491520,573440,577536};
constexpr int TOTAL_W   = 581632;   // fp16 elements in swizzled blob

struct Ptr11 { const float* p[11]; };

// ---------------------------------------------------------------------------
// Weight pre-swizzle (R7 layout, unchanged): ntile innermost; 256-out layers:
// blob[((kc*16 + ntile)*64 + lane)*8 + j]; heads: blob[(kc*64 + lane)*8 + j].
// Semantics: W[remap(kc*32 + (lane>>4)*8 + j)][ntile*16 + (lane&15)], fp16,
// 0 if padded (A-frag for mfma_f32_16x16x32_f16).
// ---------------------------------------------------------------------------
__global__ void prep_kernel(Ptr11 wp, _Float16* __restrict__ ws) {
  int tid = blockIdx.x * blockDim.x + threadIdx.x;
  if (tid >= TOTAL_W) return;
  int L = 0;
#pragma unroll
  for (int i = 1; i < 11; ++i) if (tid >= OFF_A[i]) L = i;
  int e    = tid - OFF_A[L];
  int j    = e & 7;
  int lane = (e >> 3) & 63;
  int blk  = e >> 9;
  int kc, nt;
  if (L <= 8) { kc = blk >> 4; nt = blk & 15; }
  else        { kc = blk;      nt = 0; }
  int kpad = kc * 32 + ((lane >> 4) << 3) + j;
  int n    = nt * 16 + (lane & 15);
  int k;
  if      (L == 0) k = (kpad < 63) ? kpad : -1;                               // g1_0: din 63 pad->64
  else if (L == 5) k = (kpad < 64) ? ((kpad < 63) ? kpad : -1) : kpad - 1;    // g2_0: [pe_x 63|f1 256]
  else if (L == 8) k = (kpad < 64) ? ((kpad < 39) ? kpad : -1) : kpad - 25;   // c_0:  [pe_d 39|f2 256]
  else             k = kpad;                                                  // din 256 exact
  int dout = (L == 9) ? 3 : ((L == 10) ? 1 : 256);
  float v = 0.f;
  if (k >= 0 && n < dout) v = wp.p[L][k * dout + n];
  ws[tid] = (_Float16)v;
}

// ---------------------------------------------------------------------------
// One 256-out linear layer; wave cg computes rows [0,64) x cols [cg*64,+64).
// A-prefetch distance 2: aE/aO are caller-owned and arrive PRE-LOADED with
// chunks 0/1 (loaded across the previous layer's epilogue+barrier). Inside
// the loop, a buffer is refilled for chunk k+2 immediately after the batch
// that consumes chunk k -> ~620 cyc slack. Tail refills them with the NEXT
// layer's chunks 0/1. B stays dist-1 (LDS latency ~130 << 310 slack).
// Dual-base swizzle SR (R9). All indices compile-time (R1 lesson).
// ---------------------------------------------------------------------------
template <int PE_CH, int H_CH, bool RELU>
__device__ __forceinline__ void do_layer(_Float16* lds, int rd, int wr,
                                         const _Float16* __restrict__ blob,
                                         const _Float16* __restrict__ nblob,
                                         int bias_idx, int cg, int lane,
                                         half8 aE[4], half8 aO[4]) {
  constexpr int KCH = PE_CH + H_CH;   // even (2, 8, or 10)
  const int l15  = lane & 15;
  const int quad = lane >> 4;
  const int s7   = l15 & 7;          // swizzle key (row&7 == l15&7)
  const int c1   = s7 >> 2;          // chunk-granule xor bit
  const int q3   = (quad ^ (s7 & 3));

  f32x4 acc[4][4];
#pragma unroll
  for (int mt = 0; mt < 4; ++mt)
#pragma unroll
    for (int nt = 0; nt < 4; ++nt) acc[mt][nt] = (f32x4)0.f;

  half8 bE[4], bO[4];

  const _Float16* ap  = blob  + ((size_t)(cg * 256 + lane)) * 8;
  const _Float16* nap = nblob + ((size_t)(cg * 256 + lane)) * 8;
  const _Float16* pebase = lds + PE_OFF + l15 * 64 + q3 * 8;
  const _Float16* hbase  = lds + rd + l15 * 256 + q3 * 8;
  const int co = c1 << 5;            // 32-half parity correction
  const _Float16* peE = pebase + co;
  const _Float16* peO = pebase - co;
  const _Float16* hbE = hbase + co;
  const _Float16* hbO = hbase - co;

#define LOADA(dst, base, KCG)                                                 \
  {                                                                           \
    const _Float16* apk = (base) + (size_t)(KCG) * 8192;                      \
    _Pragma("unroll") for (int nt = 0; nt < 4; ++nt)                          \
        dst[nt] = *(const half8*)(apk + nt * 512);                            \
  }

#define LOADB(bb, KCG)                                                        \
  {                                                                           \
    if ((KCG) < PE_CH) {                                                      \
      const _Float16* bpp = (((KCG) & 1) ? peO : peE) + (KCG) * 32;           \
      _Pragma("unroll") for (int mt = 0; mt < 4; ++mt)                        \
          bb[mt] = *(const half8*)(bpp + mt * 1024);                          \
    } else {                                                                  \
      const int U = (KCG) - PE_CH;                                            \
      const _Float16* bpp = ((U & 1) ? hbO : hbE) + U * 32;                   \
      _Pragma("unroll") for (int mt = 0; mt < 4; ++mt)                        \
          bb[mt] = *(const half8*)(bpp + mt * 4096);                          \
    }                                                                         \
  }

#define DO_MFMA(ab, bb)                                                       \
  {                                                                           \
    _Pragma("unroll") for (int mt = 0; mt < 4; ++mt)                          \
        _Pragma("unroll") for (int nt = 0; nt < 4; ++nt)                      \
            acc[mt][nt] = MFMA_F16(ab[nt], bb[mt], acc[mt][nt], 0, 0, 0);     \
  }

  LOADB(bE, 0)                       // H/PE-dependent: cannot cross barrier
#pragma unroll
  for (int kk = 0; kk < KCH; kk += 2) {
    LOADB(bO, kk + 1)
    DO_MFMA(aE, bE)                  // chunk kk: a loaded >=2 batches ago
    if (kk + 2 < KCH) {
      LOADA(aE, ap, kk + 2)          // refill for kk+2 (620 cyc slack)
      LOADB(bE, kk + 2)
    } else {
      LOADA(aE, nap, 0)              // cross-layer prefetch: next chunk 0
    }
    DO_MFMA(aO, bO)                  // chunk kk+1
    if (kk + 3 < KCH) {
      LOADA(aO, ap, kk + 3)
    } else {
      LOADA(aO, nap, 1)              // cross-layer prefetch: next chunk 1
    }
  }
#undef LOADA
#undef LOADB
#undef DO_MFMA

  // Epilogue: bias from LDS (staged once), write to the OTHER H buffer.
  const int qb = quad >> 1, q1 = quad & 1;
  _Float16* wbase = lds + wr + l15 * 256 + cg * 64 + q1 * 4;
  _Float16* wps[4] = { wbase + (((0 | qb) ^ s7) << 3),
                       wbase + (((2 | qb) ^ s7) << 3),
                       wbase + (((4 | qb) ^ s7) << 3),
                       wbase + (((6 | qb) ^ s7) << 3) };
  const _Float16* bb_ = lds + BIAS_OFF + bias_idx * 256 + cg * 64 + quad * 4;
  f32x4 bf[4];
#pragma unroll
  for (int nt = 0; nt < 4; ++nt) {
    half4v bh = *(const half4v*)(bb_ + nt * 16);
    bf[nt] = f32x4{ (float)bh[0], (float)bh[1], (float)bh[2], (float)bh[3] };
  }
#pragma unroll
  for (int mt = 0; mt < 4; ++mt) {
#pragma unroll
    for (int nt = 0; nt < 4; ++nt) {
      f32x4 v = acc[mt][nt] + bf[nt];
      if (RELU) {
        v.x = fmaxf(v.x, 0.f); v.y = fmaxf(v.y, 0.f);
        v.z = fmaxf(v.z, 0.f); v.w = fmaxf(v.w, 0.f);
      }
      half4v hv = { (_Float16)v.x, (_Float16)v.y, (_Float16)v.z, (_Float16)v.w };
      *(half4v*)(wps[nt] + mt * 4096) = hv;
    }
  }
  __syncthreads();   // writes to wr visible; everyone done reading rd
}

// Head (sig / c_1): NT=1 blob, K=256 over H at rd; wave w rows [w*16,+16).
__device__ __forceinline__ f32x4 head_mt(const _Float16* lds, int rd,
                                         const _Float16* __restrict__ blob,
                                         int w, int lane) {
  const int l15  = lane & 15;
  const int quad = lane >> 4;
  const int s7   = l15 & 7;
  const int c1   = s7 >> 2;
  const int q3   = (quad ^ (s7 & 3));
  const _Float16* hb = lds + rd + (w * 16 + l15) * 256 + q3 * 8;
  f32x4 res = (f32x4)0.f;
#pragma unroll
  for (int kc = 0; kc < 8; ++kc) {
    half8 a = *(const half8*)(blob + (kc * 64 + lane) * 8);
    half8 b = *(const half8*)(hb + ((kc ^ c1) << 5));
    res = MFMA_F16(a, b, res, 0, 0, 0);
  }
  return res;
}

// Positional encoding: f = tid&63 loop-invariant -> classify once per thread.
__device__ __forceinline__ void pe_pass(_Float16* lds, const float* __restrict__ src,
                                        int row0, int tid, int nfeat) {
  const int f  = tid & 63;
  const int rb = tid >> 6;
  const int fg = f >> 3, f7 = f & 7;
  int mode, c = 0, use_cos = 0;
  float freq = 0.f;
  if (f < 3) { mode = 0; c = f; }
  else if (f < nfeat) {
    int g = f - 3, li = g / 6, rem = g - li * 6;
    use_cos = (rem >= 3); c = use_cos ? rem - 3 : rem;
    freq = (float)(1 << li); mode = 1;
  } else mode = 2;
#pragma unroll
  for (int t = 0; t < 16; ++t) {
    int r = rb + t * 4;
    float v = 0.f;
    if (mode == 0) v = src[(row0 + r) * 3 + c];
    else if (mode == 1) {
      float a = src[(row0 + r) * 3 + c] * freq;
      v = use_cos ? __cosf(a) : __sinf(a);
    }
    lds[PE_OFF + r * 64 + (((fg ^ (r & 7)) << 3) | f7)] = (_Float16)v;
  }
}

__global__ __launch_bounds__(256, 2) void nerf_kernel(
    const _Float16* __restrict__ ws, const float* __restrict__ x,
    const float* __restrict__ dirp, Ptr11 bp, float* __restrict__ out) {
  extern __shared__ _Float16 lds[];
  const int tid  = threadIdx.x;
  const int lane = tid & 63;
  const int w    = tid >> 6;       // wave 0..3 (= col-group cg)
  const int l15  = lane & 15;
  const int quad = lane >> 4;
  const int row0 = blockIdx.x * M_ROWS;

  // ---- prefetch g1_0 chunks 0 AND 1 A-frags (hide L2 behind pe_pass) ----
  half8 aE[4], aO[4];
  {
    const _Float16* apk = ws + ((size_t)(w * 256 + lane)) * 8;
#pragma unroll
    for (int nt = 0; nt < 4; ++nt) {
      aE[nt] = *(const half8*)(apk + nt * 512);
      aO[nt] = *(const half8*)(apk + 8192 + nt * 512);
    }
  }

  // ---- pe_x -> PE buffer; biases -> LDS (f16, once) ----
  pe_pass(lds, x, row0, tid, 63);
#pragma unroll
  for (int L = 0; L < 9; ++L)
    lds[BIAS_OFF + L * 256 + tid] = (_Float16)bp.p[L][tid];
  __syncthreads();

  // ---- G1 (rd/wr alternate B0/B1; f1 lands in B0) ----
  do_layer<2, 0, true >(lds, B0_OFF, B0_OFF, ws + OFF_A[0], ws + OFF_A[1], 0, w, lane, aE, aO);
  do_layer<0, 8, true >(lds, B0_OFF, B1_OFF, ws + OFF_A[1], ws + OFF_A[2], 1, w, lane, aE, aO);
  do_layer<0, 8, true >(lds, B1_OFF, B0_OFF, ws + OFF_A[2], ws + OFF_A[3], 2, w, lane, aE, aO);
  do_layer<0, 8, true >(lds, B0_OFF, B1_OFF, ws + OFF_A[3], ws + OFF_A[4], 3, w, lane, aE, aO);
  do_layer<0, 8, false>(lds, B1_OFF, B0_OFF, ws + OFF_A[4], ws + OFF_A[5], 4, w, lane, aE, aO);
  // ---- G2: f2 lands in B1 ----
  do_layer<2, 8, true >(lds, B0_OFF, B1_OFF, ws + OFF_A[5], ws + OFF_A[6], 5, w, lane, aE, aO);
  do_layer<0, 8, true >(lds, B1_OFF, B0_OFF, ws + OFF_A[6], ws + OFF_A[7], 6, w, lane, aE, aO);
  do_layer<0, 8, false>(lds, B0_OFF, B1_OFF, ws + OFF_A[7], ws + OFF_A[8], 7, w, lane, aE, aO);

  // ---- sigma head reads f2@B1; pe_d overwrites PE (pe_x dead) ----
  f32x4 sa = head_mt(lds, B1_OFF, ws + OFF_A[10], w, lane);
  float sigv = sa[0] + bp.p[10][0];   // valid in quad==0 lanes
  pe_pass(lds, dirp, row0, tid, 39);
  __syncthreads();   // pe_d visible before c_0

  // ---- color: c_0 [pe_d|f2@B1] -> B0 (ReLU), c_1 reads B0 ----
  do_layer<2, 8, true>(lds, B1_OFF, B0_OFF, ws + OFF_A[8], ws, 8, w, lane, aE, aO);
  f32x4 ca = head_mt(lds, B0_OFF, ws + OFF_A[9], w, lane);
  if (quad == 0) {
    f32x4 o = { ca[0] + bp.p[9][0], ca[1] + bp.p[9][1], ca[2] + bp.p[9][2], sigv };
    *(f32x4*)(out + (size_t)(row0 + w * 16 + l15) * 4) = o;
  }
}

}  // namespace

extern "C" void kernel_launch(void* const* d_in, const int* in_sizes, int n_in,
                              void* d_out, int out_size, void* d_ws, size_t ws_size,
                              hipStream_t stream) {
  const float* x   = (const float*)d_in[0];
  const float* dir = (const float*)d_in[1];
  Ptr11 wp, bp;
  for (int i = 0; i < 11; ++i) {
    wp.p[i] = (const float*)d_in[2 + 2 * i];
    bp.p[i] = (const float*)d_in[3 + 2 * i];
  }
  _Float16* ws = (_Float16*)d_ws;
  float* out = (float*)d_out;

  hipFuncSetAttribute((const void*)nerf_kernel,
                      hipFuncAttributeMaxDynamicSharedMemorySize, (int)LDS_BYTES);

  prep_kernel<<<TOTAL_W / 256, 256, 0, stream>>>(wp, ws);
  nerf_kernel<<<262144 / M_ROWS, 256, LDS_BYTES, stream>>>(ws, x, dir, bp, out);
}